// Round 1
// 801.787 us; speedup vs baseline: 1.4065x; 1.4065x over previous
//
#include <hip/hip_runtime.h>
#include <stdint.h>

// Problem constants (from setup_inputs): N=1e6, C=96, coords in [0,256).
#define CHAN 96
#define CHAN4 24                    // 96 floats = 24 float4
#define KEY_WORDS (1u << 23)        // 2^29 bits / 64 bits per word = 8,388,608 words
#define SCAN_BLOCKS 8192            // 8192 blocks * 1024 words = KEY_WORDS
#define WORDS_PER_BLOCK 1024        // 256 threads * 4 words

// key = (batch<<21) | ((x>>1)<<14) | ((y>>1)<<7) | (z>>1)
// Order-preserving w.r.t. lexicographic order of (batch, x&~1, y&~1, z&~1).
__device__ __forceinline__ unsigned int make_key(int4 c) {
  return ((unsigned int)c.x << 21) |
         (((unsigned int)c.y >> 1) << 14) |
         (((unsigned int)c.z >> 1) << 7) |
         ((unsigned int)c.w >> 1);
}

// Sorted-unique rank of key. wp2 holds the exclusive popcount prefix at every
// EVEN word; the odd-word correction popcount comes from the same 16B line.
__device__ __forceinline__ unsigned int rank_of(unsigned int key,
                                                const unsigned long long* __restrict__ bm,
                                                const unsigned int* __restrict__ wp2) {
  unsigned int w = key >> 6, bit = key & 63u;
  ulonglong2 pair = ((const ulonglong2*)bm)[w >> 1];
  unsigned long long word = (w & 1u) ? pair.y : pair.x;
  unsigned int r = wp2[w >> 1] + (unsigned int)__popcll(word & ((1ull << bit) - 1ull));
  if (w & 1u) r += (unsigned int)__popcll(pair.x);
  return r;
}

// atomicOr's old value gives first-arrival for free: exactly one point per cell
// sees its bit unset -> representative. Stragglers (~1k of 1e6) go to a list.
__global__ void k_set_bits(const int4* __restrict__ coords, int N,
                           unsigned long long* __restrict__ bm,
                           unsigned char* __restrict__ flags,
                           unsigned int* __restrict__ multi,
                           unsigned int* __restrict__ nmulti) {
  int i = blockIdx.x * blockDim.x + threadIdx.x;
  if (i >= N) return;
  unsigned int key = make_key(coords[i]);
  unsigned long long bit = 1ull << (key & 63u);
  unsigned long long old = atomicOr(&bm[key >> 6], bit);
  bool rep = (old & bit) == 0ull;
  flags[i] = rep ? (unsigned char)1 : (unsigned char)0;
  if (!rep) {
    unsigned int slot = atomicAdd(nmulti, 1u);
    multi[slot] = (unsigned int)i;
  }
}

// Per-block popcount sums over 1024 words -> bs[block]
__global__ void k_block_sums(const unsigned long long* __restrict__ bm,
                             unsigned int* __restrict__ bs) {
  __shared__ unsigned int sh[256];
  int t = threadIdx.x;
  size_t base = (size_t)blockIdx.x * WORDS_PER_BLOCK + (size_t)t * 4;
  unsigned int s = 0;
#pragma unroll
  for (int j = 0; j < 4; j++) s += (unsigned int)__popcll(bm[base + j]);
  sh[t] = s;
  __syncthreads();
  for (int off = 128; off > 0; off >>= 1) {
    if (t < off) sh[t] += sh[t + off];
    __syncthreads();
  }
  if (t == 0) bs[blockIdx.x] = sh[0];
}

// Exclusive scan of bs[8192] in place; also writes total popcount M.
__global__ void k_scan_bs(unsigned int* __restrict__ bs,
                          unsigned int* __restrict__ total) {
  __shared__ unsigned int sh[256];
  int t = threadIdx.x;
  unsigned int local[32];
  unsigned int sum = 0;
#pragma unroll
  for (int j = 0; j < 32; j++) { local[j] = bs[t * 32 + j]; sum += local[j]; }
  sh[t] = sum;
  __syncthreads();
  for (int off = 1; off < 256; off <<= 1) {
    unsigned int x = (t >= off) ? sh[t - off] : 0u;
    __syncthreads();
    sh[t] += x;
    __syncthreads();
  }
  if (t == 255) *total = sh[255];  // M = number of unique cells
  unsigned int run = sh[t] - sum;  // exclusive prefix of this thread's chunk
#pragma unroll
  for (int j = 0; j < 32; j++) { bs[t * 32 + j] = run; run += local[j]; }
}

// Write global exclusive popcount prefix per EVEN word: wp2[w>>1] (16 MB).
__global__ void k_word_prefix(const unsigned long long* __restrict__ bm,
                              const unsigned int* __restrict__ bs,
                              unsigned int* __restrict__ wp2) {
  __shared__ unsigned int sh[256];
  int t = threadIdx.x;
  size_t base = (size_t)blockIdx.x * WORDS_PER_BLOCK + (size_t)t * 4;
  unsigned int c[4];
  unsigned int sum = 0;
#pragma unroll
  for (int j = 0; j < 4; j++) { c[j] = (unsigned int)__popcll(bm[base + j]); sum += c[j]; }
  sh[t] = sum;
  __syncthreads();
  for (int off = 1; off < 256; off <<= 1) {
    unsigned int x = (t >= off) ? sh[t - off] : 0u;
    __syncthreads();
    sh[t] += x;
    __syncthreads();
  }
  unsigned int run = bs[blockIdx.x] + (sh[t] - sum);
  wp2[(base >> 1) + 0] = run;                  // prefix before word base+0
  wp2[(base >> 1) + 1] = run + c[0] + c[1];    // prefix before word base+2
}

// Representatives: NO atomics. Plain-store dest rank and the packed
// (cn, cn*px, cn*py, cn*pz) centroid accumulator -> ONE random line per point.
// Stragglers are patched later by k_straggler (kernel-boundary ordered).
__global__ void k_rank(const int4* __restrict__ coords,
                       const float* __restrict__ points,
                       const float* __restrict__ count,
                       const unsigned char* __restrict__ flags, int N,
                       const unsigned long long* __restrict__ bm,
                       const unsigned int* __restrict__ wp2,
                       unsigned int* __restrict__ dest_of_src,
                       float4* __restrict__ tmp) {
  int i = blockIdx.x * blockDim.x + threadIdx.x;
  if (i >= N) return;
  unsigned int rank = rank_of(make_key(coords[i]), bm, wp2);
  if (flags[i]) {
    float cn = count[i];
    float4 t4;
    t4.x = cn;
    t4.y = cn * points[(size_t)i * 3 + 0];
    t4.z = cn * points[(size_t)i * 3 + 1];
    t4.w = cn * points[(size_t)i * 3 + 2];
    dest_of_src[i] = rank;
    tmp[rank] = t4;
  } else {
    dest_of_src[i] = 0xFFFFFFFFu;
  }
}

// Scatter copy: stream feats coalescedly (read side sequential), write each
// representative row to its destination rank (full 3x128B lines, aligned).
__global__ void k_scatter_feats(const float4* __restrict__ feats4,
                                const unsigned int* __restrict__ dest_of_src,
                                float4* __restrict__ feats_out4, int N) {
  int c = threadIdx.x;  // float4 slot within row
#pragma unroll
  for (int j = 0; j < 2; j++) {
    int r = blockIdx.x * 16 + threadIdx.y + j * 8;
    if (r >= N) continue;
    unsigned int dest = dest_of_src[r];
    if (dest != 0xFFFFFFFFu) {
      float4 v = feats4[(size_t)r * CHAN4 + c];
      feats_out4[(size_t)dest * CHAN4 + c] = v;
    }
  }
}

__device__ __forceinline__ void atomic_max_float(float* addr, float val) {
  unsigned int* a = (unsigned int*)addr;
  unsigned int cur = *a;
  float curf = __uint_as_float(cur);
  while (val > curf) {
    unsigned int prev = atomicCAS(a, cur, __float_as_uint(val));
    if (prev == cur) break;
    cur = prev;
    curf = __uint_as_float(cur);
  }
}

// Merge non-representative points (~0.1%): add centroid contribution into tmp
// and atomic-max their feats into the representative's output row.
// 4 threads per entry (24 channels each) to cut the serial CAS chain.
__global__ void k_straggler(const int4* __restrict__ coords,
                            const float* __restrict__ points,
                            const float* __restrict__ count,
                            const float* __restrict__ feats,
                            const unsigned int* __restrict__ nmulti,
                            const unsigned int* __restrict__ multi,
                            const unsigned long long* __restrict__ bm,
                            const unsigned int* __restrict__ wp2,
                            float* __restrict__ tmp,
                            float* __restrict__ feats_out) {
  unsigned int n4 = *nmulti * 4u;
  unsigned int stride = gridDim.x * blockDim.x;
  for (unsigned int t = blockIdx.x * blockDim.x + threadIdx.x; t < n4; t += stride) {
    unsigned int idx = t >> 2;
    unsigned int part = t & 3u;
    unsigned int i = multi[idx];
    unsigned int rank = rank_of(make_key(coords[i]), bm, wp2);
    if (part == 0u) {
      float cn = count[i];
      atomicAdd(&tmp[(size_t)rank * 4 + 0], cn);
      atomicAdd(&tmp[(size_t)rank * 4 + 1], cn * points[(size_t)i * 3 + 0]);
      atomicAdd(&tmp[(size_t)rank * 4 + 2], cn * points[(size_t)i * 3 + 1]);
      atomicAdd(&tmp[(size_t)rank * 4 + 3], cn * points[(size_t)i * 3 + 2]);
    }
    int c0 = (int)part * 24;
    for (int c = c0; c < c0 + 24; c++) {
      atomic_max_float(&feats_out[(size_t)rank * CHAN + c], feats[(size_t)i * CHAN + c]);
    }
  }
}

// One sequential pass: rows < M get the centroid division + count; rows >= M
// (the padding segments) get zeros everywhere. Replaces the 16MB output memset
// and the old per-row npts read.
__global__ void k_finalize(const float4* __restrict__ tmp,
                           const unsigned int* __restrict__ total, int N,
                           float* __restrict__ pts_out,
                           float* __restrict__ cnt_out,
                           float4* __restrict__ feats_out4) {
  int r = blockIdx.x * blockDim.x + threadIdx.x;
  if (r >= N) return;
  unsigned int M = *total;
  if ((unsigned int)r < M) {
    float4 t = tmp[r];
    float c = t.x;
    float d = (c > 0.f) ? c : 1.f;
    cnt_out[r] = c;
    pts_out[(size_t)r * 3 + 0] = t.y / d;
    pts_out[(size_t)r * 3 + 1] = t.z / d;
    pts_out[(size_t)r * 3 + 2] = t.w / d;
  } else {
    cnt_out[r] = 0.f;
    pts_out[(size_t)r * 3 + 0] = 0.f;
    pts_out[(size_t)r * 3 + 1] = 0.f;
    pts_out[(size_t)r * 3 + 2] = 0.f;
    float4 z = make_float4(0.f, 0.f, 0.f, 0.f);
    for (int c = 0; c < CHAN4; c++) feats_out4[(size_t)r * CHAN4 + c] = z;
  }
}

extern "C" void kernel_launch(void* const* d_in, const int* in_sizes, int n_in,
                              void* d_out, int out_size, void* d_ws, size_t ws_size,
                              hipStream_t stream) {
  const int4* coords  = (const int4*)d_in[0];
  const float* feats  = (const float*)d_in[1];
  const float* points = (const float*)d_in[2];
  const float* count  = (const float*)d_in[3];
  const int N = in_sizes[3];  // count has N elements

  // Workspace layout (~109 MB):
  char* ws = (char*)d_ws;
  unsigned long long* bm = (unsigned long long*)ws;                        // 64 MB
  unsigned int* wp2 = (unsigned int*)(ws + (size_t)KEY_WORDS * 8);         // 16 MB
  float4* tmp = (float4*)(ws + (size_t)KEY_WORDS * 8 +
                          (size_t)(KEY_WORDS / 2) * 4);                    // 16 MB (16B-aligned)
  unsigned int* multi = (unsigned int*)(tmp + N);                          // 4 MB
  unsigned int* dest_of_src = multi + N;                                   // 4 MB
  unsigned int* bs = dest_of_src + N;                                      // 32 KB
  unsigned int* total = bs + SCAN_BLOCKS;                                  // 4 B
  unsigned int* nmulti = total + 1;                                        // 4 B
  unsigned char* flags = (unsigned char*)(nmulti + 1);                     // 1 MB

  float* feats_out = (float*)d_out;
  float* pts_out = feats_out + (size_t)N * CHAN;
  float* cnt_out = pts_out + (size_t)N * 3;

  hipMemsetAsync(bm, 0, (size_t)KEY_WORDS * 8, stream);
  hipMemsetAsync(nmulti, 0, 4, stream);

  const int TB = 256;
  const int nb = (N + TB - 1) / TB;
  k_set_bits<<<nb, TB, 0, stream>>>(coords, N, bm, flags, multi, nmulti);
  k_block_sums<<<SCAN_BLOCKS, 256, 0, stream>>>(bm, bs);
  k_scan_bs<<<1, 256, 0, stream>>>(bs, total);
  k_word_prefix<<<SCAN_BLOCKS, 256, 0, stream>>>(bm, bs, wp2);
  k_rank<<<nb, TB, 0, stream>>>(coords, points, count, flags, N, bm, wp2,
                                dest_of_src, tmp);
  dim3 cblock(CHAN4, 8);
  k_scatter_feats<<<(N + 15) / 16, cblock, 0, stream>>>(
      (const float4*)feats, dest_of_src, (float4*)feats_out, N);
  k_straggler<<<128, 256, 0, stream>>>(coords, points, count, feats, nmulti,
                                       multi, bm, wp2, (float*)tmp, feats_out);
  k_finalize<<<nb, TB, 0, stream>>>(tmp, total, N, pts_out, cnt_out,
                                    (float4*)feats_out);
}